// Round 8
// baseline (315.070 us; speedup 1.0000x reference)
//
#include <hip/hip_runtime.h>
#include <hip/hip_bf16.h>

// N=10000 nodes, F=256, H=256, E=320000 edges.
//
// W1 = [W1a | W1b]:  U' = x @ W1a^T + b1 (bias folded), V = x @ W1b^T
// out[e] = sigmoid(b2 + sum_j relu(U'[row][j] + V[col][j]) * W2[j])
// uv layout: uv[node][0:256]=U', uv[node][256:512]=V, bf16 (1 KB/row).
//
// R8: counting-sort edges by row>>4 (625 buckets). E/N=32 avg edges/row ->
// sorted processing makes U-gather L1/L2-resident (160 MB -> ~first touch),
// leaving only the 5.12 MB V-half as a random working set (~L2-sized).
// R6 lesson kept: phases stay separate kernels (independent reg budgets).
// Harness tax (unremovable): ~46us 268MB d_ws re-poison fill per window.

typedef __attribute__((ext_vector_type(8))) short bf16x8;
typedef __attribute__((ext_vector_type(4))) float f32x4;

__device__ __forceinline__ unsigned short f2bf(float f) {
    __hip_bfloat16 h = __float2bfloat16(f);
    return *reinterpret_cast<unsigned short*>(&h);
}

#define NBUCK 625   // row>>4, rows 0..9999

// ---------------------------------------------------------------------------
// Sort kernel A: histogram of row>>4.
// ---------------------------------------------------------------------------
__global__ __launch_bounds__(256) void hist_kernel(const int* __restrict__ ei,
                                                   int* __restrict__ counts, int E) {
    int e = blockIdx.x * 256 + threadIdx.x;
    if (e < E) atomicAdd(&counts[ei[e] >> 4], 1);
}

// ---------------------------------------------------------------------------
// Sort kernel B: exclusive scan of 625 counts -> cursor. One block.
// ---------------------------------------------------------------------------
__global__ __launch_bounds__(1024) void scan_kernel(const int* __restrict__ counts,
                                                    int* __restrict__ cursor) {
    __shared__ int s[1024];
    int t = threadIdx.x;
    s[t] = (t < NBUCK) ? counts[t] : 0;
    __syncthreads();
#pragma unroll
    for (int d = 1; d < 1024; d <<= 1) {
        int v = (t >= d) ? s[t - d] : 0;
        __syncthreads();
        s[t] += v;
        __syncthreads();
    }
    if (t < NBUCK) cursor[t] = (t == 0) ? 0 : s[t - 1];
}

// ---------------------------------------------------------------------------
// Sort kernel C: scatter edge (row, col, idx) to its bucket position.
// ---------------------------------------------------------------------------
__global__ __launch_bounds__(256) void scatter_kernel(const int* __restrict__ ei,
                                                      int* __restrict__ cursor,
                                                      int* __restrict__ srow,
                                                      int* __restrict__ scol,
                                                      int* __restrict__ sidx, int E) {
    int e = blockIdx.x * 256 + threadIdx.x;
    if (e < E) {
        int row = ei[e];
        int pos = atomicAdd(&cursor[row >> 4], 1);
        srow[pos] = row;
        scol[pos] = ei[E + e];
        sidx[pos] = e;
    }
}

// ---------------------------------------------------------------------------
// Kernel 0: convert W1 (256x512 fp32) to bf16. Tiny (~2us).
// ---------------------------------------------------------------------------
__global__ __launch_bounds__(256) void convert_w(const float* __restrict__ w1,
                                                 unsigned short* __restrict__ wb,
                                                 int nw4) {
    int i = blockIdx.x * 256 + threadIdx.x;
    if (i < nw4) {
        float4 v = ((const float4*)w1)[i];
        ushort4 o = {f2bf(v.x), f2bf(v.y), f2bf(v.z), f2bf(v.w)};
        ((ushort4*)wb)[i] = o;
    }
}

// ---------------------------------------------------------------------------
// Kernel 1 (R5, proven): block = 16 rows x 512 cols. Wave w owns cols
// w*128..+127. Per ktile: stage A (16x32 fp32->bf16) in dbuf LDS (stride 40,
// 2-way alias = free); 1 ds_read_b128 A-frag + 8x16B B-frags (L2-resident wb)
// + 8 MFMA 16x16x32. C/D: col=lane&15, row=(lane>>4)*4+reg. b1 folded into U.
// ---------------------------------------------------------------------------
__global__ __launch_bounds__(256) void gemm_mfma(const float* __restrict__ x,
                                                 const unsigned short* __restrict__ wb,
                                                 const float* __restrict__ b1,
                                                 unsigned short* __restrict__ uv,
                                                 int M) {
    __shared__ __align__(16) unsigned short As[2][16][40];

    const int t    = threadIdx.x;
    const int wave = t >> 6;
    const int lane = t & 63;
    const int lm   = lane & 15;
    const int lq   = lane >> 4;
    const int lk   = lq * 8;
    const int m0   = blockIdx.x * 16;

    const int srow = t >> 4;
    const int sk   = (t & 15) * 2;
    const int grow = m0 + srow;
    const float* sptr = x + (size_t)(grow < M ? grow : (M - 1)) * 256 + sk;

    const int half    = wave >> 1;
    const int colbase = wave * 128;
    const int rowbase = (wave & 1) * 128;
    const unsigned short* bpre =
        wb + (size_t)(rowbase + lm) * 512 + half * 256 + lk;

    f32x4 acc[8];
#pragma unroll
    for (int j = 0; j < 8; ++j) acc[j] = f32x4{0.f, 0.f, 0.f, 0.f};

    float2 apref = *(const float2*)(sptr);

#pragma unroll
    for (int it = 0; it < 8; ++it) {
        const int kt  = it * 32;
        const int cur = it & 1;
        unsigned int lo = ((unsigned int)f2bf(apref.x));
        unsigned int hi = ((unsigned int)f2bf(apref.y)) << 16;
        *(unsigned int*)&As[cur][srow][sk] = lo | hi;
        if (it < 7) apref = *(const float2*)(sptr + kt + 32);
        __syncthreads();
        bf16x8 a = *(const bf16x8*)&As[cur][lm][lk];
#pragma unroll
        for (int j = 0; j < 8; ++j) {
            bf16x8 b = *(const bf16x8*)(bpre + (size_t)j * 16 * 512 + kt);
            acc[j] = __builtin_amdgcn_mfma_f32_16x16x32_bf16(a, b, acc[j], 0, 0, 0);
        }
    }

    const int row0 = m0 + lq * 4;
#pragma unroll
    for (int j = 0; j < 8; ++j) {
        const int col  = colbase + j * 16 + lm;
        const float badd = half ? 0.f : b1[col];
#pragma unroll
        for (int r = 0; r < 4; ++r) {
            if (row0 + r < M)
                uv[(size_t)(row0 + r) * 512 + col] = f2bf(acc[j][r] + badd);
        }
    }
}

// ---------------------------------------------------------------------------
// Kernel 2: pair-pipelined edge phase over SORTED edges. 4 edges/batch
// (g=lane>>4 slot, c=lane&15 col chunk, 32B/lane per row); two batches per
// iteration. Consecutive positions share row-buckets -> U loads hit L1/L2.
// Reads (srow, scol, sidx); writes out[sidx] (random 4B, L2-absorbed).
// ---------------------------------------------------------------------------
__global__ __launch_bounds__(256) void edge_kernel(const unsigned short* __restrict__ uv,
                                                   const int* __restrict__ srowp,
                                                   const int* __restrict__ scolp,
                                                   const int* __restrict__ sidxp,
                                                   const float* __restrict__ w2,
                                                   const float* __restrict__ b2p,
                                                   float* __restrict__ out, int E) {
    const int lane = threadIdx.x & 63;
    const int g = lane >> 4;
    const int c = lane & 15;
    const int wid  = (blockIdx.x * blockDim.x + threadIdx.x) >> 6;
    const int nwav = (gridDim.x * blockDim.x) >> 6;
    const int nb   = E >> 2;

    float w2r[16];
#pragma unroll
    for (int i = 0; i < 4; ++i)
        *(float4*)&w2r[i * 4] = *(const float4*)(w2 + c * 16 + i * 4);
    const float b2 = b2p[0];

    for (int b = wid; b < nb; b += 2 * nwav) {
        const int bB = b + nwav;
        const bool has2 = bB < nb;

        const int p0 = b * 4 + g;
        const int r0 = srowp[p0];
        const int c0 = scolp[p0];
        const int i0 = sidxp[p0];
        const int p1 = has2 ? bB * 4 + g : p0;
        const int r1 = srowp[p1];
        const int c1 = scolp[p1];
        const int i1 = sidxp[p1];

        const uint4* up0 = (const uint4*)(uv + (size_t)r0 * 512 + c * 16);
        const uint4* vp0 = (const uint4*)(uv + (size_t)c0 * 512 + 256 + c * 16);
        const uint4* up1 = (const uint4*)(uv + (size_t)r1 * 512 + c * 16);
        const uint4* vp1 = (const uint4*)(uv + (size_t)c1 * 512 + 256 + c * 16);

        uint4 ua0 = up0[0], ua1 = up0[1];
        uint4 va0 = vp0[0], va1 = vp0[1];
        uint4 ub0 = up1[0], ub1 = up1[1];
        uint4 vb0 = vp1[0], vb1 = vp1[1];

        unsigned int uw[8], vw[8];
        float2 p2;
        float p;

        // ---- batch A ----
        *(uint4*)&uw[0] = ua0; *(uint4*)&uw[4] = ua1;
        *(uint4*)&vw[0] = va0; *(uint4*)&vw[4] = va1;
        p2 = float2{0.f, 0.f};
#pragma unroll
        for (int i = 0; i < 8; ++i) {
            float2 u2 = {__uint_as_float(uw[i] << 16),
                         __uint_as_float(uw[i] & 0xffff0000u)};
            float2 v2 = {__uint_as_float(vw[i] << 16),
                         __uint_as_float(vw[i] & 0xffff0000u)};
            float2 s2 = {fmaxf(u2.x + v2.x, 0.f), fmaxf(u2.y + v2.y, 0.f)};
            p2.x = fmaf(s2.x, w2r[2 * i], p2.x);
            p2.y = fmaf(s2.y, w2r[2 * i + 1], p2.y);
        }
        p = p2.x + p2.y;
#pragma unroll
        for (int off = 1; off < 16; off <<= 1)
            p += __shfl_xor(p, off, 64);
        if (c == 0) out[i0] = 1.f / (1.f + __expf(-(p + b2)));

        // ---- batch B ----
        if (has2) {
            *(uint4*)&uw[0] = ub0; *(uint4*)&uw[4] = ub1;
            *(uint4*)&vw[0] = vb0; *(uint4*)&vw[4] = vb1;
            p2 = float2{0.f, 0.f};
#pragma unroll
            for (int i = 0; i < 8; ++i) {
                float2 u2 = {__uint_as_float(uw[i] << 16),
                             __uint_as_float(uw[i] & 0xffff0000u)};
                float2 v2 = {__uint_as_float(vw[i] << 16),
                             __uint_as_float(vw[i] & 0xffff0000u)};
                float2 s2 = {fmaxf(u2.x + v2.x, 0.f), fmaxf(u2.y + v2.y, 0.f)};
                p2.x = fmaf(s2.x, w2r[2 * i], p2.x);
                p2.y = fmaf(s2.y, w2r[2 * i + 1], p2.y);
            }
            p = p2.x + p2.y;
#pragma unroll
            for (int off = 1; off < 16; off <<= 1)
                p += __shfl_xor(p, off, 64);
            if (c == 0) out[i1] = 1.f / (1.f + __expf(-(p + b2)));
        }
    }
}

extern "C" void kernel_launch(void* const* d_in, const int* in_sizes, int n_in,
                              void* d_out, int out_size, void* d_ws, size_t ws_size,
                              hipStream_t stream) {
    const float* x  = (const float*)d_in[0];
    const int*   ei = (const int*)d_in[1];
    const float* W1 = (const float*)d_in[2];
    const float* b1 = (const float*)d_in[3];
    const float* W2 = (const float*)d_in[4];
    const float* b2 = (const float*)d_in[5];
    float* out = (float*)d_out;

    const int N = in_sizes[0] / 256;   // 10000
    const int E = in_sizes[1] / 2;     // 320000

    // workspace layout
    unsigned short* uv = (unsigned short*)d_ws;        // N*512 bf16 (10.24 MB)
    unsigned short* wb = uv + (size_t)N * 512;         // 256*512 bf16 (256 KB)
    int* counts = (int*)(wb + 256 * 512);              // NBUCK
    int* cursor = counts + NBUCK;                      // NBUCK
    int* srow   = cursor + NBUCK;                      // E
    int* scol   = srow + E;                            // E
    int* sidx   = scol + E;                            // E

    hipMemsetAsync(counts, 0, NBUCK * sizeof(int), stream);
    hist_kernel<<<(E + 255) / 256, 256, 0, stream>>>(ei, counts, E);
    scan_kernel<<<1, 1024, 0, stream>>>(counts, cursor);
    scatter_kernel<<<(E + 255) / 256, 256, 0, stream>>>(ei, cursor, srow, scol, sidx, E);

    const int nw4 = (256 * 512) / 4;
    convert_w<<<(nw4 + 255) / 256, 256, 0, stream>>>(W1, wb, nw4);

    gemm_mfma<<<(N + 15) / 16, 256, 0, stream>>>(x, wb, b1, uv, N);

    edge_kernel<<<2048, 256, 0, stream>>>(uv, srow, scol, sidx, W2, b2, out, E);
}

// Round 9
// 225.342 us; speedup vs baseline: 1.3982x; 1.3982x over previous
//
#include <hip/hip_runtime.h>
#include <hip/hip_bf16.h>
#include <hip/hip_cooperative_groups.h>

namespace cg = cooperative_groups;

// N=10000 nodes, F=256, H=256, E=320000 edges.
//
// W1 = [W1a | W1b]:  U' = x @ W1a^T + b1 (bias folded), V = x @ W1b^T
// out[e] = sigmoid(b2 + sum_j relu(U'[row][j] + V[col][j]) * W2[j])
// uv layout: uv[node][0:256]=U', uv[node][256:512]=V, bf16 (1 KB/row).
//
// R8 lesson: global atomicAdd-with-return over 625 cursors = 512-deep
// serial chains = 96us. R9: one cooperative sort kernel, LDS atomics only,
// deterministic global bases via block-histogram + scan. Edge kernel walks
// sorted edges with per-wave contiguous runs -> U rows L1/L2-resident.
// R6 lesson kept: compute phases stay separate kernels.

typedef __attribute__((ext_vector_type(8))) short bf16x8;
typedef __attribute__((ext_vector_type(4))) float f32x4;

__device__ __forceinline__ unsigned short f2bf(float f) {
    __hip_bfloat16 h = __float2bfloat16(f);
    return *reinterpret_cast<unsigned short*>(&h);
}

#define NBUCK 625      // row>>4, rows 0..9999
#define NBPAD 640      // padded bucket count (multiple of 64)
#define SORTB 80       // sort blocks
#define CHUNK 4000     // edges per sort block (80*4000 = 320000)

// ---------------------------------------------------------------------------
// Cooperative sort kernel: 80 blocks x 640 threads.
// A: block-local LDS hist of row>>4 over contiguous chunk -> hist[k*80+b]
// B: block 0: per-bucket prefix over blocks + bucket-base scan (absolute)
// C: scatter via LDS cursors (short chains) -> srow/scol/sidx
// ---------------------------------------------------------------------------
__global__ __launch_bounds__(640) void sort_kernel(const int* __restrict__ ei,
                                                   int* __restrict__ hist,
                                                   int* __restrict__ srow,
                                                   int* __restrict__ scol,
                                                   int* __restrict__ sidx, int E) {
    __shared__ int lh[NBPAD];
    cg::grid_group grid = cg::this_grid();
    const int t = threadIdx.x;
    const int b = blockIdx.x;
    const int e0 = b * CHUNK;
    const int e1 = (e0 + CHUNK < E) ? e0 + CHUNK : E;

    // ---- A: local histogram ----
    if (t < NBPAD) lh[t] = 0;
    __syncthreads();
    for (int e = e0 + t; e < e1; e += 640)
        atomicAdd(&lh[ei[e] >> 4], 1);
    __syncthreads();
    if (t < NBPAD) hist[t * SORTB + b] = lh[t];

    grid.sync();

    // ---- B: block 0 computes absolute bases into hist ----
    if (b == 0) {
        __shared__ int tot[NBPAD];
        if (t < NBPAD) {
            int s = 0;
#pragma unroll 4
            for (int bb = 0; bb < SORTB; ++bb) {
                int v = hist[t * SORTB + bb];
                hist[t * SORTB + bb] = s;     // per-bucket exclusive prefix
                s += v;
            }
            tot[t] = s;
        }
        __syncthreads();
        // Hillis-Steele inclusive scan over 640 totals
        for (int d = 1; d < NBPAD; d <<= 1) {
            int v = (t < NBPAD && t >= d) ? tot[t - d] : 0;
            __syncthreads();
            if (t < NBPAD) tot[t] += v;
            __syncthreads();
        }
        if (t < NBPAD) {
            int base = (t == 0) ? 0 : tot[t - 1];   // exclusive bucket base
#pragma unroll 4
            for (int bb = 0; bb < SORTB; ++bb)
                hist[t * SORTB + bb] += base;
        }
    }

    grid.sync();

    // ---- C: scatter with LDS cursors ----
    if (t < NBPAD) lh[t] = hist[t * SORTB + b];
    __syncthreads();
    for (int e = e0 + t; e < e1; e += 640) {
        int row = ei[e];
        int pos = atomicAdd(&lh[row >> 4], 1);
        srow[pos] = row;
        scol[pos] = ei[E + e];
        sidx[pos] = e;
    }
}

// ---------------------------------------------------------------------------
// Kernel 0: convert W1 (256x512 fp32) to bf16. Tiny (~2us).
// ---------------------------------------------------------------------------
__global__ __launch_bounds__(256) void convert_w(const float* __restrict__ w1,
                                                 unsigned short* __restrict__ wb,
                                                 int nw4) {
    int i = blockIdx.x * 256 + threadIdx.x;
    if (i < nw4) {
        float4 v = ((const float4*)w1)[i];
        ushort4 o = {f2bf(v.x), f2bf(v.y), f2bf(v.z), f2bf(v.w)};
        ((ushort4*)wb)[i] = o;
    }
}

// ---------------------------------------------------------------------------
// Kernel 1 (R5, proven): block = 16 rows x 512 cols. Wave w owns cols
// w*128..+127. Per ktile: stage A (16x32 fp32->bf16) in dbuf LDS (stride 40,
// 2-way alias = free); 1 ds_read_b128 A-frag + 8x16B B-frags (L2-resident wb)
// + 8 MFMA 16x16x32. C/D: col=lane&15, row=(lane>>4)*4+reg. b1 folded into U.
// ---------------------------------------------------------------------------
__global__ __launch_bounds__(256) void gemm_mfma(const float* __restrict__ x,
                                                 const unsigned short* __restrict__ wb,
                                                 const float* __restrict__ b1,
                                                 unsigned short* __restrict__ uv,
                                                 int M) {
    __shared__ __align__(16) unsigned short As[2][16][40];

    const int t    = threadIdx.x;
    const int wave = t >> 6;
    const int lane = t & 63;
    const int lm   = lane & 15;
    const int lq   = lane >> 4;
    const int lk   = lq * 8;
    const int m0   = blockIdx.x * 16;

    const int srow = t >> 4;
    const int sk   = (t & 15) * 2;
    const int grow = m0 + srow;
    const float* sptr = x + (size_t)(grow < M ? grow : (M - 1)) * 256 + sk;

    const int half    = wave >> 1;
    const int colbase = wave * 128;
    const int rowbase = (wave & 1) * 128;
    const unsigned short* bpre =
        wb + (size_t)(rowbase + lm) * 512 + half * 256 + lk;

    f32x4 acc[8];
#pragma unroll
    for (int j = 0; j < 8; ++j) acc[j] = f32x4{0.f, 0.f, 0.f, 0.f};

    float2 apref = *(const float2*)(sptr);

#pragma unroll
    for (int it = 0; it < 8; ++it) {
        const int kt  = it * 32;
        const int cur = it & 1;
        unsigned int lo = ((unsigned int)f2bf(apref.x));
        unsigned int hi = ((unsigned int)f2bf(apref.y)) << 16;
        *(unsigned int*)&As[cur][srow][sk] = lo | hi;
        if (it < 7) apref = *(const float2*)(sptr + kt + 32);
        __syncthreads();
        bf16x8 a = *(const bf16x8*)&As[cur][lm][lk];
#pragma unroll
        for (int j = 0; j < 8; ++j) {
            bf16x8 b = *(const bf16x8*)(bpre + (size_t)j * 16 * 512 + kt);
            acc[j] = __builtin_amdgcn_mfma_f32_16x16x32_bf16(a, b, acc[j], 0, 0, 0);
        }
    }

    const int row0 = m0 + lq * 4;
#pragma unroll
    for (int j = 0; j < 8; ++j) {
        const int col  = colbase + j * 16 + lm;
        const float badd = half ? 0.f : b1[col];
#pragma unroll
        for (int r = 0; r < 4; ++r) {
            if (row0 + r < M)
                uv[(size_t)(row0 + r) * 512 + col] = f2bf(acc[j][r] + badd);
        }
    }
}

// ---------------------------------------------------------------------------
// Kernel 2: edge phase over SORTED edges. 4 edges/batch (g=lane>>4 slot,
// c=lane&15 col chunk, 32B/lane per row). Each wave owns 10 CONSECUTIVE
// batches (40 consecutive sorted edges) -> same 16-row U bucket (8 KB)
// stays L1-resident; V-half remains the only random stream.
// ---------------------------------------------------------------------------
__global__ __launch_bounds__(256) void edge_kernel(const unsigned short* __restrict__ uv,
                                                   const int* __restrict__ srowp,
                                                   const int* __restrict__ scolp,
                                                   const int* __restrict__ sidxp,
                                                   const float* __restrict__ w2,
                                                   const float* __restrict__ b2p,
                                                   float* __restrict__ out, int E) {
    const int lane = threadIdx.x & 63;
    const int g = lane >> 4;
    const int c = lane & 15;
    const int wave = threadIdx.x >> 6;
    const int nb   = E >> 2;                      // 80000 batches
    const int bpw  = 10;                          // 2048 blk * 4 waves * 10 = 81920
    const int base = (blockIdx.x * 4 + wave) * bpw;

    float w2r[16];
#pragma unroll
    for (int i = 0; i < 4; ++i)
        *(float4*)&w2r[i * 4] = *(const float4*)(w2 + c * 16 + i * 4);
    const float b2 = b2p[0];

    for (int i = 0; i < bpw; ++i) {
        const int b = base + i;
        if (b >= nb) break;
        const int p0 = b * 4 + g;
        const int row = srowp[p0];
        const int col = scolp[p0];
        const int idx = sidxp[p0];

        const uint4* up = (const uint4*)(uv + (size_t)row * 512 + c * 16);
        const uint4* vp = (const uint4*)(uv + (size_t)col * 512 + 256 + c * 16);
        uint4 u0 = up[0], u1 = up[1];
        uint4 v0 = vp[0], v1 = vp[1];

        unsigned int uw[8], vw[8];
        *(uint4*)&uw[0] = u0; *(uint4*)&uw[4] = u1;
        *(uint4*)&vw[0] = v0; *(uint4*)&vw[4] = v1;

        float2 p2 = {0.f, 0.f};
#pragma unroll
        for (int j = 0; j < 8; ++j) {
            float2 u2 = {__uint_as_float(uw[j] << 16),
                         __uint_as_float(uw[j] & 0xffff0000u)};
            float2 v2 = {__uint_as_float(vw[j] << 16),
                         __uint_as_float(vw[j] & 0xffff0000u)};
            float2 s2 = {fmaxf(u2.x + v2.x, 0.f), fmaxf(u2.y + v2.y, 0.f)};
            p2.x = fmaf(s2.x, w2r[2 * j], p2.x);
            p2.y = fmaf(s2.y, w2r[2 * j + 1], p2.y);
        }
        float p = p2.x + p2.y;

#pragma unroll
        for (int off = 1; off < 16; off <<= 1)
            p += __shfl_xor(p, off, 64);

        if (c == 0) out[idx] = 1.f / (1.f + __expf(-(p + b2)));
    }
}

extern "C" void kernel_launch(void* const* d_in, const int* in_sizes, int n_in,
                              void* d_out, int out_size, void* d_ws, size_t ws_size,
                              hipStream_t stream) {
    const float* x  = (const float*)d_in[0];
    const int*   ei = (const int*)d_in[1];
    const float* W1 = (const float*)d_in[2];
    const float* b1 = (const float*)d_in[3];
    const float* W2 = (const float*)d_in[4];
    const float* b2 = (const float*)d_in[5];
    float* out = (float*)d_out;

    int N = in_sizes[0] / 256;   // 10000
    int E = in_sizes[1] / 2;     // 320000

    // workspace layout
    unsigned short* uv = (unsigned short*)d_ws;        // N*512 bf16 (10.24 MB)
    unsigned short* wb = uv + (size_t)N * 512;         // 256*512 bf16 (256 KB)
    int* hist = (int*)(wb + 256 * 512);                // NBPAD*SORTB (204 KB)
    int* srow = hist + NBPAD * SORTB;                  // E
    int* scol = srow + E;                              // E
    int* sidx = scol + E;                              // E

    void* sargs[] = {(void*)&ei, (void*)&hist, (void*)&srow, (void*)&scol,
                     (void*)&sidx, (void*)&E};
    hipLaunchCooperativeKernel((void*)sort_kernel, dim3(SORTB), dim3(640),
                               sargs, 0, stream);

    const int nw4 = (256 * 512) / 4;
    convert_w<<<(nw4 + 255) / 256, 256, 0, stream>>>(W1, wb, nw4);

    gemm_mfma<<<(N + 15) / 16, 256, 0, stream>>>(x, wb, b1, uv, N);

    edge_kernel<<<2048, 256, 0, stream>>>(uv, srow, scol, sidx, W2, b2, out, E);
}

// Round 10
// 131.518 us; speedup vs baseline: 2.3956x; 1.7134x over previous
//
#include <hip/hip_runtime.h>
#include <hip/hip_bf16.h>

// N=10000 nodes, F=256, H=256, E=320000 edges.
//
// W1 = [W1a | W1b]:  U' = x @ W1a^T + b1 (bias folded), V = x @ W1b^T
// out[e] = sigmoid(b2 + sum_j relu(U'[row][j] + V[col][j]) * W2[j])
// uv layout: uv[node][0:256]=U', uv[node][256:512]=V, bf16 (1 KB/row).
//
// FINAL STRUCTURE (R7 revert). Journal of failed alternatives:
//  - R6: fusing phases into one cooperative kernel -> shared reg allocation
//    spilled (WRITE_SIZE 10->54 MB), 288us. Keep kernels separate.
//  - R8: global-atomic counting sort for row-locality: 96us (atomic-return
//    serial chains). R9: LDS-atomic cooperative sort: 75us (single-block
//    scan + random scatter latency). Sort cost >> max locality gain (~20us).
//  - R7: deeper edge ILP (2x outstanding gathers): neutral -> edge is L2
//    line-request-throughput bound (~2.56M lines / 32 slices ~= 33us floor),
//    not latency bound.
// Harness tax in every timed window: ~46us 268MB d_ws re-poison fill +
// restores/gaps (~25us) — not controllable from kernel code.

typedef __attribute__((ext_vector_type(8))) short bf16x8;
typedef __attribute__((ext_vector_type(4))) float f32x4;

__device__ __forceinline__ unsigned short f2bf(float f) {
    __hip_bfloat16 h = __float2bfloat16(f);
    return *reinterpret_cast<unsigned short*>(&h);
}

// ---------------------------------------------------------------------------
// Kernel 0: convert W1 (256x512 fp32) to bf16. Tiny (~2us).
// ---------------------------------------------------------------------------
__global__ __launch_bounds__(256) void convert_w(const float* __restrict__ w1,
                                                 unsigned short* __restrict__ wb,
                                                 int nw4) {
    int i = blockIdx.x * 256 + threadIdx.x;
    if (i < nw4) {
        float4 v = ((const float4*)w1)[i];
        ushort4 o = {f2bf(v.x), f2bf(v.y), f2bf(v.z), f2bf(v.w)};
        ((ushort4*)wb)[i] = o;
    }
}

// ---------------------------------------------------------------------------
// Kernel 1: block = 16 rows x 512 cols. Wave w owns cols w*128..+127
// (8 n-tiles). Per ktile (K=32): stage A (16x32 fp32->bf16) into dbuf LDS
// (stride 40: 2-way bank alias = free); 1 ds_read_b128 A-frag + 8x16B
// B-frags from L2-resident wb + 8 MFMA 16x16x32.
// C/D: col=lane&15, row=(lane>>4)*4+reg. b1 folded into U half.
// 625 blocks -> ~2.4/CU: enough TLP to hide B-load latency (R4 showed 314
// blocks was latency-bound at MfmaUtil 2%).
// ---------------------------------------------------------------------------
__global__ __launch_bounds__(256) void gemm_mfma(const float* __restrict__ x,
                                                 const unsigned short* __restrict__ wb,
                                                 const float* __restrict__ b1,
                                                 unsigned short* __restrict__ uv,
                                                 int M) {
    __shared__ __align__(16) unsigned short As[2][16][40];

    const int t    = threadIdx.x;
    const int wave = t >> 6;
    const int lane = t & 63;
    const int lm   = lane & 15;
    const int lq   = lane >> 4;
    const int lk   = lq * 8;
    const int m0   = blockIdx.x * 16;

    const int srow = t >> 4;
    const int sk   = (t & 15) * 2;
    const int grow = m0 + srow;
    const float* sptr = x + (size_t)(grow < M ? grow : (M - 1)) * 256 + sk;

    const int half    = wave >> 1;
    const int colbase = wave * 128;
    const int rowbase = (wave & 1) * 128;
    const unsigned short* bpre =
        wb + (size_t)(rowbase + lm) * 512 + half * 256 + lk;

    f32x4 acc[8];
#pragma unroll
    for (int j = 0; j < 8; ++j) acc[j] = f32x4{0.f, 0.f, 0.f, 0.f};

    float2 apref = *(const float2*)(sptr);

#pragma unroll
    for (int it = 0; it < 8; ++it) {
        const int kt  = it * 32;
        const int cur = it & 1;
        unsigned int lo = ((unsigned int)f2bf(apref.x));
        unsigned int hi = ((unsigned int)f2bf(apref.y)) << 16;
        *(unsigned int*)&As[cur][srow][sk] = lo | hi;
        if (it < 7) apref = *(const float2*)(sptr + kt + 32);
        __syncthreads();
        bf16x8 a = *(const bf16x8*)&As[cur][lm][lk];
#pragma unroll
        for (int j = 0; j < 8; ++j) {
            bf16x8 b = *(const bf16x8*)(bpre + (size_t)j * 16 * 512 + kt);
            acc[j] = __builtin_amdgcn_mfma_f32_16x16x32_bf16(a, b, acc[j], 0, 0, 0);
        }
    }

    const int row0 = m0 + lq * 4;
#pragma unroll
    for (int j = 0; j < 8; ++j) {
        const int col  = colbase + j * 16 + lm;
        const float badd = half ? 0.f : b1[col];
#pragma unroll
        for (int r = 0; r < 4; ++r) {
            if (row0 + r < M)
                uv[(size_t)(row0 + r) * 512 + col] = f2bf(acc[j][r] + badd);
        }
    }
}

// ---------------------------------------------------------------------------
// Kernel 2: edge phase. 4 edges per batch (g=lane>>4 slot, c=lane&15 col
// chunk, 32B/lane per row); two independent batches per iteration with all
// 8x16B gather loads issued before compute. Bound by L2 line-request
// throughput (~33us floor for 2.56M line fetches), measured ~40us.
// ---------------------------------------------------------------------------
__global__ __launch_bounds__(256) void edge_kernel(const unsigned short* __restrict__ uv,
                                                   const int* __restrict__ ei,
                                                   const float* __restrict__ w2,
                                                   const float* __restrict__ b2p,
                                                   float* __restrict__ out, int E) {
    const int lane = threadIdx.x & 63;
    const int g = lane >> 4;
    const int c = lane & 15;
    const int wid  = (blockIdx.x * blockDim.x + threadIdx.x) >> 6;
    const int nwav = (gridDim.x * blockDim.x) >> 6;
    const int nb   = E >> 2;

    float w2r[16];
#pragma unroll
    for (int i = 0; i < 4; ++i)
        *(float4*)&w2r[i * 4] = *(const float4*)(w2 + c * 16 + i * 4);
    const float b2 = b2p[0];

    for (int b = wid; b < nb; b += 2 * nwav) {
        const int bB = b + nwav;
        const bool has2 = bB < nb;

        const int e0 = b * 4 + g;
        const int r0 = ei[e0];
        const int c0 = ei[E + e0];
        const int e1 = has2 ? bB * 4 + g : e0;
        const int r1 = ei[e1];
        const int c1 = ei[E + e1];

        const uint4* up0 = (const uint4*)(uv + (size_t)r0 * 512 + c * 16);
        const uint4* vp0 = (const uint4*)(uv + (size_t)c0 * 512 + 256 + c * 16);
        const uint4* up1 = (const uint4*)(uv + (size_t)r1 * 512 + c * 16);
        const uint4* vp1 = (const uint4*)(uv + (size_t)c1 * 512 + 256 + c * 16);

        // issue all 8 gather loads before any compute
        uint4 ua0 = up0[0], ua1 = up0[1];
        uint4 va0 = vp0[0], va1 = vp0[1];
        uint4 ub0 = up1[0], ub1 = up1[1];
        uint4 vb0 = vp1[0], vb1 = vp1[1];

        unsigned int uw[8], vw[8];
        float2 p2;
        float p;

        // ---- batch A ----
        *(uint4*)&uw[0] = ua0; *(uint4*)&uw[4] = ua1;
        *(uint4*)&vw[0] = va0; *(uint4*)&vw[4] = va1;
        p2 = float2{0.f, 0.f};
#pragma unroll
        for (int i = 0; i < 8; ++i) {
            float2 u2 = {__uint_as_float(uw[i] << 16),
                         __uint_as_float(uw[i] & 0xffff0000u)};
            float2 v2 = {__uint_as_float(vw[i] << 16),
                         __uint_as_float(vw[i] & 0xffff0000u)};
            float2 s2 = {fmaxf(u2.x + v2.x, 0.f), fmaxf(u2.y + v2.y, 0.f)};
            p2.x = fmaf(s2.x, w2r[2 * i], p2.x);
            p2.y = fmaf(s2.y, w2r[2 * i + 1], p2.y);
        }
        p = p2.x + p2.y;
#pragma unroll
        for (int off = 1; off < 16; off <<= 1)
            p += __shfl_xor(p, off, 64);
        if (c == 0) out[e0] = 1.f / (1.f + __expf(-(p + b2)));

        // ---- batch B ----
        if (has2) {
            *(uint4*)&uw[0] = ub0; *(uint4*)&uw[4] = ub1;
            *(uint4*)&vw[0] = vb0; *(uint4*)&vw[4] = vb1;
            p2 = float2{0.f, 0.f};
#pragma unroll
            for (int i = 0; i < 8; ++i) {
                float2 u2 = {__uint_as_float(uw[i] << 16),
                             __uint_as_float(uw[i] & 0xffff0000u)};
                float2 v2 = {__uint_as_float(vw[i] << 16),
                             __uint_as_float(vw[i] & 0xffff0000u)};
                float2 s2 = {fmaxf(u2.x + v2.x, 0.f), fmaxf(u2.y + v2.y, 0.f)};
                p2.x = fmaf(s2.x, w2r[2 * i], p2.x);
                p2.y = fmaf(s2.y, w2r[2 * i + 1], p2.y);
            }
            p = p2.x + p2.y;
#pragma unroll
            for (int off = 1; off < 16; off <<= 1)
                p += __shfl_xor(p, off, 64);
            if (c == 0) out[e1] = 1.f / (1.f + __expf(-(p + b2)));
        }
    }
}

extern "C" void kernel_launch(void* const* d_in, const int* in_sizes, int n_in,
                              void* d_out, int out_size, void* d_ws, size_t ws_size,
                              hipStream_t stream) {
    const float* x  = (const float*)d_in[0];
    const int*   ei = (const int*)d_in[1];
    const float* W1 = (const float*)d_in[2];
    const float* b1 = (const float*)d_in[3];
    const float* W2 = (const float*)d_in[4];
    const float* b2 = (const float*)d_in[5];
    float* out = (float*)d_out;

    const int N = in_sizes[0] / 256;   // 10000
    const int E = in_sizes[1] / 2;     // 320000

    unsigned short* uv = (unsigned short*)d_ws;        // N*512 bf16 (10.24 MB)
    unsigned short* wb = uv + (size_t)N * 512;         // 256*512 bf16 (256 KB)

    const int nw4 = (256 * 512) / 4;
    convert_w<<<(nw4 + 255) / 256, 256, 0, stream>>>(W1, wb, nw4);

    gemm_mfma<<<(N + 15) / 16, 256, 0, stream>>>(x, wb, b1, uv, N);

    edge_kernel<<<2048, 256, 0, stream>>>(uv, ei, W2, b2, out, E);
}

// Round 11
// 116.821 us; speedup vs baseline: 2.6970x; 1.1258x over previous
//
#include <hip/hip_runtime.h>
#include <hip/hip_bf16.h>

// N=10000 nodes, F=256, H=256, E=320000 edges.
//
// W1 = [W1a | W1b]:  U' = x @ W1a^T + b1 (bias folded), V = x @ W1b^T
// out[e] = sigmoid(b2 + sum_j relu(U'[row][j] + V[col][j]) * W2[j])
// uv layout (R11: fp8 e4m3, HW cvt): uv[node] = 512 BYTES:
//   bytes [0:256] = U' cols, bytes [256:512] = V cols.
// Halves the edge-gather traffic (2.56M -> 1.28M L2 lines) and shrinks the
// table to 5.12 MB (~per-XCD L2 size). Encode+decode both use gfx950 HW
// fp8 cvt -> self-consistent. Error budget: e4m3 ~2.4% RMS on sigma~0.41
// u/v values -> logit RMS ~0.006, worst ~0.026 -> output absmax ~0.008
// vs threshold 0.0138.
//
// Journal: R6 fused coop kernel -> reg spill (288us). R8/R9 sort-for-
// locality -> sort costs 75-96us >> ~20us locality gain. R7 deeper ILP ->
// neutral (edge is line-throughput bound, not latency). Harness tax ~50us.

typedef __attribute__((ext_vector_type(8))) short bf16x8;
typedef __attribute__((ext_vector_type(4))) float f32x4;
typedef __attribute__((ext_vector_type(2))) float f32x2;

__device__ __forceinline__ unsigned short f2bf(float f) {
    __hip_bfloat16 h = __float2bfloat16(f);
    return *reinterpret_cast<unsigned short*>(&h);
}

__device__ __forceinline__ unsigned char f2fp8(float f) {
    // HW round-to-nearest fp8 e4m3 (OCP on gfx950), low byte of packed result
    return (unsigned char)(__builtin_amdgcn_cvt_pk_fp8_f32(f, f, 0, false) & 0xff);
}

// ---------------------------------------------------------------------------
// Kernel 0: convert W1 (256x512 fp32) to bf16. Tiny (~2us).
// ---------------------------------------------------------------------------
__global__ __launch_bounds__(256) void convert_w(const float* __restrict__ w1,
                                                 unsigned short* __restrict__ wb,
                                                 int nw4) {
    int i = blockIdx.x * 256 + threadIdx.x;
    if (i < nw4) {
        float4 v = ((const float4*)w1)[i];
        ushort4 o = {f2bf(v.x), f2bf(v.y), f2bf(v.z), f2bf(v.w)};
        ((ushort4*)wb)[i] = o;
    }
}

// ---------------------------------------------------------------------------
// Kernel 1 (R5 core, fp8 epilogue): block = 16 rows x 512 cols. Wave w owns
// cols w*128..+127. Per ktile: stage A (16x32 fp32->bf16) in dbuf LDS
// (stride 40, 2-way alias = free); 1 ds_read_b128 A-frag + 8x16B B-frags
// (L2-resident wb) + 8 MFMA 16x16x32. C/D: col=lane&15, row=(lane>>4)*4+reg.
// b1 folded into U half; epilogue quantizes to fp8 (byte stores).
// ---------------------------------------------------------------------------
__global__ __launch_bounds__(256) void gemm_mfma(const float* __restrict__ x,
                                                 const unsigned short* __restrict__ wb,
                                                 const float* __restrict__ b1,
                                                 unsigned char* __restrict__ uv,
                                                 int M) {
    __shared__ __align__(16) unsigned short As[2][16][40];

    const int t    = threadIdx.x;
    const int wave = t >> 6;
    const int lane = t & 63;
    const int lm   = lane & 15;
    const int lq   = lane >> 4;
    const int lk   = lq * 8;
    const int m0   = blockIdx.x * 16;

    const int srow = t >> 4;
    const int sk   = (t & 15) * 2;
    const int grow = m0 + srow;
    const float* sptr = x + (size_t)(grow < M ? grow : (M - 1)) * 256 + sk;

    const int half    = wave >> 1;
    const int colbase = wave * 128;
    const int rowbase = (wave & 1) * 128;
    const unsigned short* bpre =
        wb + (size_t)(rowbase + lm) * 512 + half * 256 + lk;

    f32x4 acc[8];
#pragma unroll
    for (int j = 0; j < 8; ++j) acc[j] = f32x4{0.f, 0.f, 0.f, 0.f};

    float2 apref = *(const float2*)(sptr);

#pragma unroll
    for (int it = 0; it < 8; ++it) {
        const int kt  = it * 32;
        const int cur = it & 1;
        unsigned int lo = ((unsigned int)f2bf(apref.x));
        unsigned int hi = ((unsigned int)f2bf(apref.y)) << 16;
        *(unsigned int*)&As[cur][srow][sk] = lo | hi;
        if (it < 7) apref = *(const float2*)(sptr + kt + 32);
        __syncthreads();
        bf16x8 a = *(const bf16x8*)&As[cur][lm][lk];
#pragma unroll
        for (int j = 0; j < 8; ++j) {
            bf16x8 b = *(const bf16x8*)(bpre + (size_t)j * 16 * 512 + kt);
            acc[j] = __builtin_amdgcn_mfma_f32_16x16x32_bf16(a, b, acc[j], 0, 0, 0);
        }
    }

    const int row0 = m0 + lq * 4;
#pragma unroll
    for (int j = 0; j < 8; ++j) {
        const int col  = colbase + j * 16 + lm;          // 0..511
        const int cin  = col & 255;                      // col within half
        const float badd = half ? 0.f : b1[cin];
#pragma unroll
        for (int r = 0; r < 4; ++r) {
            if (row0 + r < M)
                uv[(size_t)(row0 + r) * 512 + col] = f2fp8(acc[j][r] + badd);
        }
    }
}

// ---------------------------------------------------------------------------
// Kernel 2: edge phase over fp8 uv. 4 edges/batch (g=lane>>4 slot, c=lane&15
// col chunk); per lane ONE uint4 (16 fp8) per U row + one per V row. Two
// independent batches per iteration. Decode via HW v_cvt_pk_f32_fp8.
// ---------------------------------------------------------------------------
__global__ __launch_bounds__(256) void edge_kernel(const unsigned char* __restrict__ uv,
                                                   const int* __restrict__ ei,
                                                   const float* __restrict__ w2,
                                                   const float* __restrict__ b2p,
                                                   float* __restrict__ out, int E) {
    const int lane = threadIdx.x & 63;
    const int g = lane >> 4;
    const int c = lane & 15;
    const int wid  = (blockIdx.x * blockDim.x + threadIdx.x) >> 6;
    const int nwav = (gridDim.x * blockDim.x) >> 6;
    const int nb   = E >> 2;

    float w2r[16];
#pragma unroll
    for (int i = 0; i < 4; ++i)
        *(float4*)&w2r[i * 4] = *(const float4*)(w2 + c * 16 + i * 4);
    const float b2 = b2p[0];

    for (int b = wid; b < nb; b += 2 * nwav) {
        const int bB = b + nwav;
        const bool has2 = bB < nb;

        const int e0 = b * 4 + g;
        const int r0 = ei[e0];
        const int c0 = ei[E + e0];
        const int e1 = has2 ? bB * 4 + g : e0;
        const int r1 = ei[e1];
        const int c1 = ei[E + e1];

        // issue all 4 gather loads before any compute
        uint4 ua = *(const uint4*)(uv + (size_t)r0 * 512 + c * 16);
        uint4 va = *(const uint4*)(uv + (size_t)c0 * 512 + 256 + c * 16);
        uint4 ub = *(const uint4*)(uv + (size_t)r1 * 512 + c * 16);
        uint4 vb = *(const uint4*)(uv + (size_t)c1 * 512 + 256 + c * 16);

        unsigned int uw[4], vw[4];
        float p;

        // ---- batch A ----
        *(uint4*)&uw[0] = ua; *(uint4*)&vw[0] = va;
        {
            float2 p2 = {0.f, 0.f};
#pragma unroll
            for (int w = 0; w < 4; ++w) {
                f32x2 u01 = __builtin_amdgcn_cvt_pk_f32_fp8(uw[w], false);
                f32x2 u23 = __builtin_amdgcn_cvt_pk_f32_fp8(uw[w], true);
                f32x2 v01 = __builtin_amdgcn_cvt_pk_f32_fp8(vw[w], false);
                f32x2 v23 = __builtin_amdgcn_cvt_pk_f32_fp8(vw[w], true);
                float s0 = fmaxf(u01.x + v01.x, 0.f);
                float s1 = fmaxf(u01.y + v01.y, 0.f);
                float s2 = fmaxf(u23.x + v23.x, 0.f);
                float s3 = fmaxf(u23.y + v23.y, 0.f);
                p2.x = fmaf(s0, w2r[4 * w + 0], p2.x);
                p2.y = fmaf(s1, w2r[4 * w + 1], p2.y);
                p2.x = fmaf(s2, w2r[4 * w + 2], p2.x);
                p2.y = fmaf(s3, w2r[4 * w + 3], p2.y);
            }
            p = p2.x + p2.y;
        }
#pragma unroll
        for (int off = 1; off < 16; off <<= 1)
            p += __shfl_xor(p, off, 64);
        if (c == 0) out[e0] = 1.f / (1.f + __expf(-(p + b2)));

        // ---- batch B ----
        if (has2) {
            *(uint4*)&uw[0] = ub; *(uint4*)&vw[0] = vb;
            float2 p2 = {0.f, 0.f};
#pragma unroll
            for (int w = 0; w < 4; ++w) {
                f32x2 u01 = __builtin_amdgcn_cvt_pk_f32_fp8(uw[w], false);
                f32x2 u23 = __builtin_amdgcn_cvt_pk_f32_fp8(uw[w], true);
                f32x2 v01 = __builtin_amdgcn_cvt_pk_f32_fp8(vw[w], false);
                f32x2 v23 = __builtin_amdgcn_cvt_pk_f32_fp8(vw[w], true);
                float s0 = fmaxf(u01.x + v01.x, 0.f);
                float s1 = fmaxf(u01.y + v01.y, 0.f);
                float s2 = fmaxf(u23.x + v23.x, 0.f);
                float s3 = fmaxf(u23.y + v23.y, 0.f);
                p2.x = fmaf(s0, w2r[4 * w + 0], p2.x);
                p2.y = fmaf(s1, w2r[4 * w + 1], p2.y);
                p2.x = fmaf(s2, w2r[4 * w + 2], p2.x);
                p2.y = fmaf(s3, w2r[4 * w + 3], p2.y);
            }
            p = p2.x + p2.y;
#pragma unroll
            for (int off = 1; off < 16; off <<= 1)
                p += __shfl_xor(p, off, 64);
            if (c == 0) out[e1] = 1.f / (1.f + __expf(-(p + b2)));
        }
    }
}

extern "C" void kernel_launch(void* const* d_in, const int* in_sizes, int n_in,
                              void* d_out, int out_size, void* d_ws, size_t ws_size,
                              hipStream_t stream) {
    const float* x  = (const float*)d_in[0];
    const int*   ei = (const int*)d_in[1];
    const float* W1 = (const float*)d_in[2];
    const float* b1 = (const float*)d_in[3];
    const float* W2 = (const float*)d_in[4];
    const float* b2 = (const float*)d_in[5];
    float* out = (float*)d_out;

    const int N = in_sizes[0] / 256;   // 10000
    const int E = in_sizes[1] / 2;     // 320000

    unsigned char*  uv = (unsigned char*)d_ws;            // N*512 fp8 (5.12 MB)
    unsigned short* wb = (unsigned short*)(uv + (size_t)N * 512); // 256KB bf16

    const int nw4 = (256 * 512) / 4;
    convert_w<<<(nw4 + 255) / 256, 256, 0, stream>>>(W1, wb, nw4);

    gemm_mfma<<<(N + 15) / 16, 256, 0, stream>>>(x, wb, b1, uv, N);

    edge_kernel<<<2048, 256, 0, stream>>>(uv, ei, W2, b2, out, E);
}